// Round 4
// baseline (415.432 us; speedup 1.0000x reference)
//
#include <hip/hip_runtime.h>

// Problem constants (B,C,S,E) = (8,16,512,256), fp32 in/out.
constexpr int BATCH = 8;
constexpr int CYC   = 16;
constexpr int SEQ   = 512;
constexpr int EMB   = 256;

typedef __attribute__((ext_vector_type(8))) short bf16x8;
typedef __attribute__((ext_vector_type(4))) float f32x4;

__device__ __forceinline__ unsigned short f2bf(float x) {
    unsigned int u = __float_as_uint(x);
    u += 0x7fffu + ((u >> 16) & 1u);   // RNE
    return (unsigned short)(u >> 16);
}
__device__ __forceinline__ unsigned int pk2(float lo, float hi) {
    return (unsigned int)f2bf(lo) | ((unsigned int)f2bf(hi) << 16);
}
__device__ __forceinline__ f32x4 mfma16(bf16x8 a, bf16x8 b, f32x4 c) {
    return __builtin_amdgcn_mfma_f32_16x16x32_bf16(a, b, c, 0, 0, 0);
}
// async global->LDS, 16B/lane; LDS dst = wave-uniform base + lane*16
__device__ __forceinline__ void gll16(const unsigned short* g, unsigned short* l) {
    __builtin_amdgcn_global_load_lds(
        (const __attribute__((address_space(1))) void*)g,
        (__attribute__((address_space(3))) void*)l, 16, 0, 0);
}

// ---------------------------------------------------------------------------
// Kernel 0 (fused q/k/v): W[c][e][f] fp32 -> Wblk[c][kk][f][32] bf16,
// k-blocked + XOR-chunk-swizzled: slot s of row f holds e-chunk s^((f>>1)&3).
// Makes proj's B-staging a fully contiguous 1-KB gll stream.
// grid (8 kk, 4 f-tiles, 48 = which*16+c), block 256.
// ---------------------------------------------------------------------------
__global__ __launch_bounds__(256) void wt_kernel(
    const float* __restrict__ Wq, const float* __restrict__ Wk, const float* __restrict__ Wv,
    unsigned short* __restrict__ Oq, unsigned short* __restrict__ Ok, unsigned short* __restrict__ Ov)
{
    __shared__ float tile[32][65];
    const int kk = blockIdx.x;
    const int f0 = blockIdx.y * 64;
    const int z  = blockIdx.z;
    const int which = z >> 4, c = z & 15;
    const float* W = which == 0 ? Wq : (which == 1 ? Wk : Wv);
    unsigned short* O = which == 0 ? Oq : (which == 1 ? Ok : Ov);
    const float* Wc = W + (size_t)c * EMB * EMB;
    unsigned short* Oc = O + (size_t)c * EMB * EMB;   // blocked: kk*8192 + f*32 + s*8
    const int t = threadIdx.x;
    {
        const int er = t >> 3, fc = (t & 7) * 8;
        const float4 v0 = *(const float4*)(Wc + (size_t)(kk * 32 + er) * EMB + f0 + fc);
        const float4 v1 = *(const float4*)(Wc + (size_t)(kk * 32 + er) * EMB + f0 + fc + 4);
        tile[er][fc + 0] = v0.x; tile[er][fc + 1] = v0.y;
        tile[er][fc + 2] = v0.z; tile[er][fc + 3] = v0.w;
        tile[er][fc + 4] = v1.x; tile[er][fc + 5] = v1.y;
        tile[er][fc + 6] = v1.z; tile[er][fc + 7] = v1.w;
    }
    __syncthreads();
    {
        const int fl = t >> 2, s = t & 3;
        const int f  = f0 + fl;
        const int e0 = (s ^ ((f >> 1) & 3)) * 8;
        ushort4 o0, o1;
        o0.x = f2bf(tile[e0 + 0][fl]); o0.y = f2bf(tile[e0 + 1][fl]);
        o0.z = f2bf(tile[e0 + 2][fl]); o0.w = f2bf(tile[e0 + 3][fl]);
        o1.x = f2bf(tile[e0 + 4][fl]); o1.y = f2bf(tile[e0 + 5][fl]);
        o1.z = f2bf(tile[e0 + 6][fl]); o1.w = f2bf(tile[e0 + 7][fl]);
        unsigned short* dst = Oc + (size_t)kk * 8192 + (size_t)f * 32 + s * 8;
        *(ushort4*)dst       = o0;
        *(ushort4*)(dst + 4) = o1;
    }
}

// ---------------------------------------------------------------------------
// Kernel 1 (fused q/k/v): Y = relu(X_f32 @ W + bias) * scale, bf16 out.
// Tile 64(m) x 256(n full), BK=32, FULL double buffer, ONE barrier/iter:
//   after barrier(k): issue A-loads(k+1) + gll B(k+1) -> buf^1, MFMA on buf,
//   then pack+ds_write A(k+1).  B gll is contiguous 1 KB (blocked W layout).
// grid (128 bc, 8 m, 3 qkv).  LDS 43 KB -> 3 blocks/CU.
// ---------------------------------------------------------------------------
__global__ __launch_bounds__(256, 3) void proj_kernel(
    const float* __restrict__ Xq, const float* __restrict__ Xk, const float* __restrict__ Xv,
    const unsigned short* __restrict__ Wq, const unsigned short* __restrict__ Wk,
    const unsigned short* __restrict__ Wv,
    const float* __restrict__ bq, const float* __restrict__ bk, const float* __restrict__ bv,
    unsigned short* __restrict__ Yq, unsigned short* __restrict__ Yk, unsigned short* __restrict__ Yv)
{
    __shared__ unsigned short smem[21504]; // As0 2560 | As1 2560 | Bs0 8192 | Bs1 8192
    unsigned short* Asb[2] = { smem,        smem + 2560 };
    unsigned short* Bsb[2] = { smem + 5120, smem + 13312 };

    const int bc = blockIdx.x;
    const int m0 = blockIdx.y * 64;
    const int which = blockIdx.z;
    const int c  = bc & (CYC - 1);
    const float* X = which == 0 ? Xq : (which == 1 ? Xk : Xv);
    const unsigned short* Wt = which == 0 ? Wq : (which == 1 ? Wk : Wv);
    const float* bias = which == 0 ? bq : (which == 1 ? bk : bv);
    unsigned short* Y = which == 0 ? Yq : (which == 1 ? Yk : Yv);
    const float scale = which == 0 ? 0.0625f : 1.0f;   // E^-0.5 folded into Q
    const int transposeOut = (which == 2);

    const float* Xb = X + (size_t)bc * SEQ * EMB;
    const unsigned short* Wc = Wt + (size_t)c * EMB * EMB;  // blocked layout
    const float* bb = bias + (size_t)c * EMB;
    unsigned short* Yb = Y + (size_t)bc * SEQ * EMB;

    const int tid  = threadIdx.x;
    const int lane = tid & 63, w = tid >> 6;
    const int ln   = lane & 15, quad = lane >> 4;
    const int wu   = __builtin_amdgcn_readfirstlane(w);

    const int arow  = tid >> 2;              // 0..63
    const int acol  = (tid & 3) * 8;
    const int bslot = quad ^ ((ln >> 1) & 3);

    f32x4 acc[4][4];
    for (int i = 0; i < 4; ++i)
        for (int j = 0; j < 4; ++j) acc[i][j] = (f32x4){0.f, 0.f, 0.f, 0.f};

    // --- prologue: stage k=0 ---
    {
        const unsigned short* gw = Wc + (size_t)(wu * 64) * 32 + lane * 8;
        unsigned short* lb = Bsb[0] + (wu * 64) * 32;
        for (int j = 0; j < 4; ++j) gll16(gw + j * 512, lb + j * 512);
        const float* ax = Xb + (size_t)(m0 + arow) * EMB + acol;
        const float4 a0 = *(const float4*)ax;
        const float4 a1 = *(const float4*)(ax + 4);
        int4 pk;
        pk.x = pk2(a0.x, a0.y); pk.y = pk2(a0.z, a0.w);
        pk.z = pk2(a1.x, a1.y); pk.w = pk2(a1.z, a1.w);
        *(int4*)&Asb[0][arow * 40 + acol] = pk;
    }

    for (int kk = 0; kk < 8; ++kk) {
        const int cur = kk & 1, nxt = cur ^ 1;
        __syncthreads();   // buf[cur] staged (drains gll vmcnt + ds_write lgkm)
        float4 a0n, a1n;
        if (kk < 7) {
            const float* ax = Xb + (size_t)(m0 + arow) * EMB + (kk + 1) * 32 + acol;
            a0n = *(const float4*)ax;
            a1n = *(const float4*)(ax + 4);
            const unsigned short* gw = Wc + (size_t)(kk + 1) * 8192 + (wu * 64) * 32 + lane * 8;
            unsigned short* lb = Bsb[nxt] + (wu * 64) * 32;
            for (int j = 0; j < 4; ++j) gll16(gw + j * 512, lb + j * 512);
        }
        bf16x8 af[4], bfv[4];
        for (int i = 0; i < 4; ++i)
            af[i] = *(const bf16x8*)&Asb[cur][(i * 16 + ln) * 40 + quad * 8];
        for (int j = 0; j < 4; ++j)
            bfv[j] = *(const bf16x8*)&Bsb[cur][(w * 64 + j * 16 + ln) * 32 + bslot * 8];
        for (int i = 0; i < 4; ++i)
            for (int j = 0; j < 4; ++j)
                acc[i][j] = mfma16(af[i], bfv[j], acc[i][j]);
        if (kk < 7) {
            int4 pk;
            pk.x = pk2(a0n.x, a0n.y); pk.y = pk2(a0n.z, a0n.w);
            pk.z = pk2(a1n.x, a1n.y); pk.w = pk2(a1n.z, a1n.w);
            *(int4*)&Asb[nxt][arow * 40 + acol] = pk;
        }
    }
    __syncthreads();   // done with LDS buffers; epilogue reuses smem

    // Epilogue.  C/D layout: col = lane&15, row = quad*4 + reg  [m89-verified]
    float bvj[4];
    for (int j = 0; j < 4; ++j) bvj[j] = bb[w * 64 + j * 16 + ln];

    if (!transposeOut) {
        unsigned short* ep = smem + w * 1152;  // per-wave [16][72]
        for (int i = 0; i < 4; ++i) {
            for (int j = 0; j < 4; ++j)
                for (int r = 0; r < 4; ++r)
                    ep[(quad * 4 + r) * 72 + j * 16 + ln] =
                        f2bf(fmaxf(acc[i][j][r] + bvj[j], 0.f) * scale);
            __syncthreads();
            for (int h = 0; h < 2; ++h) {
                const int cid = lane + h * 64;   // [16 rows][8 chunks]
                const int row = cid >> 3, ch = cid & 7;
                *(bf16x8*)&Yb[(size_t)(m0 + i * 16 + row) * EMB + w * 64 + ch * 8] =
                    *(const bf16x8*)&ep[row * 72 + ch * 8];
            }
            __syncthreads();
        }
    } else {
        for (int j = 0; j < 4; ++j) {
            const int fg = w * 64 + j * 16 + ln;
            for (int i = 0; i < 4; ++i) {
                const int mb = m0 + i * 16 + quad * 4;
                ushort4 u;
                u.x = f2bf(fmaxf(acc[i][j][0] + bvj[j], 0.f) * scale);
                u.y = f2bf(fmaxf(acc[i][j][1] + bvj[j], 0.f) * scale);
                u.z = f2bf(fmaxf(acc[i][j][2] + bvj[j], 0.f) * scale);
                u.w = f2bf(fmaxf(acc[i][j][3] + bvj[j], 0.f) * scale);
                *(ushort4*)&Yb[(size_t)fg * SEQ + mb] = u;
            }
        }
    }
}

// ---------------------------------------------------------------------------
// Kernel 2: attention per (b,c).  K double-buffered via contiguous gll
// (XOR chunk-swizzle in GLOBAL address -> unpadded LDS, conflict-free reads),
// V-fragments read DIRECTLY from global Vtp[e][t] (shared by 4 waves -> L1),
// no max-subtraction (scores >= 0 & bounded: q,k are relu outputs).
// 2 barriers/iter.  LDS 37.9 KB.  grid (128 bc, 8 qt).
// ---------------------------------------------------------------------------
__global__ __launch_bounds__(256, 3) void attn_kernel(
    const unsigned short* __restrict__ Qp, const unsigned short* __restrict__ Kp,
    const unsigned short* __restrict__ Vt, float* __restrict__ Out)
{
    __shared__ unsigned short Ks[2][8192];  // [32][256] unpadded, swizzled
    __shared__ unsigned short Ps[2560];     // [64][40]
    const int bc = blockIdx.x;
    const int qt = blockIdx.y;
    const unsigned short* Qb = Qp + (size_t)bc * SEQ * EMB;
    const unsigned short* Kb = Kp + (size_t)bc * SEQ * EMB;
    const unsigned short* Vb = Vt + (size_t)bc * SEQ * EMB;  // [e][t]
    float* Ob = Out + (size_t)bc * SEQ * EMB;

    const int tid  = threadIdx.x;
    const int lane = tid & 63, w = tid >> 6;
    const int ln   = lane & 15, quad = lane >> 4;
    const int wu   = __builtin_amdgcn_readfirstlane(w);

    // Q fragments resident (A-operand: A[m=lane&15][k=quad*8+j])
    bf16x8 qf[8];
    const int qrow = qt * 64 + w * 16 + ln;
    for (int ke = 0; ke < 8; ++ke)
        qf[ke] = *(const bf16x8*)(Qb + (size_t)qrow * EMB + ke * 32 + quad * 8);

    f32x4 of[16];
    for (int n = 0; n < 16; ++n) of[n] = (f32x4){0.f, 0.f, 0.f, 0.f};
    float lsum[4] = {0.f, 0.f, 0.f, 0.f};

    const int krow = wu * 8 + (lane >> 5);       // stage rows (+= j*2)
    const int kch  = lane & 31;
    const size_t voff = (size_t)ln * SEQ + quad * 8;  // V-frag per-lane offset

    // prologue: stage K tile 0
    {
        unsigned short* lb = Ks[0] + (wu * 8) * 256;
        for (int j = 0; j < 4; ++j) {
            const int row = krow + j * 2;
            const int gc  = kch ^ (row & 7);
            gll16(Kb + (size_t)row * EMB + gc * 8, lb + j * 512);
        }
    }

    for (int tt = 0; tt < 16; ++tt) {
        const int cur = tt & 1;
        __syncthreads();   // K[tt] staged; Ps free; prev PV done
        if (tt < 15) {
            const int t1 = (tt + 1) * 32;
            unsigned short* lb = Ks[cur ^ 1] + (wu * 8) * 256;
            for (int j = 0; j < 4; ++j) {
                const int row = krow + j * 2;
                const int gc  = kch ^ (row & 7);
                gll16(Kb + (size_t)(t1 + row) * EMB + gc * 8, lb + j * 512);
            }
        }
        // V group 0 (overlaps QK)
        bf16x8 vf[8];
        for (int n = 0; n < 8; ++n)
            vf[n] = *(const bf16x8*)(Vb + voff + (size_t)n * 16 * SEQ + tt * 32);

        // QK^T on swizzled Ks: slot = (ke*4+quad) ^ (ln&7)
        f32x4 sf0 = (f32x4){0.f,0.f,0.f,0.f}, sf1 = (f32x4){0.f,0.f,0.f,0.f};
        for (int ke = 0; ke < 8; ++ke) {
            const int slot = ((ke * 4 + quad) ^ (ln & 7)) * 8;
            bf16x8 b0 = *(const bf16x8*)&Ks[cur][ln * 256 + slot];
            bf16x8 b1 = *(const bf16x8*)&Ks[cur][(16 + ln) * 256 + slot];
            sf0 = mfma16(qf[ke], b0, sf0);
            sf1 = mfma16(qf[ke], b1, sf1);
        }

        float p0[4], p1[4];
        for (int r = 0; r < 4; ++r) {
            p0[r] = __expf(sf0[r]);
            p1[r] = __expf(sf1[r]);
            lsum[r] += p0[r] + p1[r];
        }
        for (int r = 0; r < 4; ++r) {
            Ps[(w * 16 + quad * 4 + r) * 40 + ln]      = f2bf(p0[r]);
            Ps[(w * 16 + quad * 4 + r) * 40 + 16 + ln] = f2bf(p1[r]);
        }
        __syncthreads();   // Ps visible

        bf16x8 af = *(const bf16x8*)&Ps[(w * 16 + ln) * 40 + quad * 8];
        for (int n = 0; n < 8; ++n)
            of[n] = mfma16(af, vf[n], of[n]);
        bf16x8 vg[8];      // V group 1 (overlaps first PV half)
        for (int n = 0; n < 8; ++n)
            vg[n] = *(const bf16x8*)(Vb + voff + (size_t)(n + 8) * 16 * SEQ + tt * 32);
        for (int n = 0; n < 8; ++n)
            of[n + 8] = mfma16(af, vg[n], of[n + 8]);
    }

    for (int off = 1; off < 16; off <<= 1)
        for (int r = 0; r < 4; ++r)
            lsum[r] += __shfl_xor(lsum[r], off, 64);
    float inv[4];
    for (int r = 0; r < 4; ++r) inv[r] = 1.0f / lsum[r];
    const int mbase = qt * 64 + w * 16 + quad * 4;
    for (int n = 0; n < 16; ++n)
        for (int r = 0; r < 4; ++r)
            Ob[(size_t)(mbase + r) * EMB + n * 16 + ln] = of[n][r] * inv[r];
}

// ---------------------------------------------------------------------------
extern "C" void kernel_launch(void* const* d_in, const int* in_sizes, int n_in,
                              void* d_out, int out_size, void* d_ws, size_t ws_size,
                              hipStream_t stream) {
    const float* query = (const float*)d_in[0];
    const float* key_  = (const float*)d_in[1];
    const float* value = (const float*)d_in[2];
    const float* wq = (const float*)d_in[3];
    const float* wk = (const float*)d_in[4];
    const float* wv = (const float*)d_in[5];
    const float* bq = (const float*)d_in[6];
    const float* bk = (const float*)d_in[7];
    const float* bv = (const float*)d_in[8];
    float* out = (float*)d_out;

    // Workspace: Wblk q/k/v bf16 (2 MiB ea) | Qp, Kp, Vtp bf16 (32 MiB ea)
    char* ws = (char*)d_ws;
    const size_t wsz = (size_t)CYC * EMB * EMB * sizeof(unsigned short);
    const size_t psz = (size_t)BATCH * CYC * SEQ * EMB * sizeof(unsigned short);
    unsigned short* Wtq = (unsigned short*)(ws);
    unsigned short* Wtk = (unsigned short*)(ws + wsz);
    unsigned short* Wtv = (unsigned short*)(ws + 2 * wsz);
    unsigned short* Qp  = (unsigned short*)(ws + 3 * wsz);
    unsigned short* Kp  = (unsigned short*)(ws + 3 * wsz + psz);
    unsigned short* Vtp = (unsigned short*)(ws + 3 * wsz + 2 * psz);

    const dim3 tb(256);
    wt_kernel<<<dim3(8, 4, 48), tb, 0, stream>>>(wq, wk, wv, Wtq, Wtk, Wtv);
    proj_kernel<<<dim3(BATCH * CYC, SEQ / 64, 3), tb, 0, stream>>>(
        query, key_, value, Wtq, Wtk, Wtv, bq, bk, bv, Qp, Kp, Vtp);
    attn_kernel<<<dim3(BATCH * CYC, SEQ / 64), tb, 0, stream>>>(Qp, Kp, Vtp, out);
}